// Round 1
// baseline (578.967 us; speedup 1.0000x reference)
//
#include <hip/hip_runtime.h>

// Fused LSTM(H=128) + 3-layer MLP head, bf16 MFMA (32x32x16), fp32 state.
// B=8192 rows, T=30 steps. 512 blocks x 256 threads (4 waves), 16 rows/block
// => 2 independent blocks/CU (OccupancyPercent ~22) so one block's compute
// fills the other's LDS/barrier/trans latency. MFMA rows 16..31 are zero-pad;
// C/D regs r<8 hold exactly rows 0..15, so all VALU epilogues run on r<8 only
// (per-CU VALU work unchanged vs 32-row blocks).
// - Weights live in VGPRs as pre-packed bf16 B-fragments (pack kernel -> d_ws).
// - Wave w owns output cols [32w,32w+32) of every GEMM; z-GEMM N-tiles at
//   g*128+32w for g=0..3 => (i,f,g,o) quadruple + c-state are in-lane.
// - Activations (x,h) use split bf16 hi+lo (error ~2^-17); o1 single bf16.
// - fp32: accumulators, c, gate nonlinearities, o2, output head, feedback p.
// - LDS A-panels: [kstep][32 rows][24 shorts] (16 data + 8 pad, 48B rows);
//   pad rows 16..31 stay zero for the whole kernel (never rewritten).

#define T_STEPS 30
#define WARM_N  24

typedef __attribute__((ext_vector_type(8)))  short short8;   // 8 bf16 = 4 VGPRs
typedef __attribute__((ext_vector_type(16))) float float16;  // MFMA 32x32 C/D

struct FeatPtrs { const float* f[7]; };

__device__ __forceinline__ short f2bf(float f){
  unsigned u = __float_as_uint(f);
  unsigned r = (u + 0x7fffu + ((u >> 16) & 1u)) >> 16;   // round-nearest-even
  return (short)r;
}
__device__ __forceinline__ float bf2f(short h){
  return __uint_as_float(((unsigned)(unsigned short)h) << 16);
}

#if __has_builtin(__builtin_amdgcn_rcpf)
#define RCP(x) __builtin_amdgcn_rcpf(x)
#else
#define RCP(x) (1.0f/(x))
#endif

__device__ __forceinline__ float sigm(float x){ return RCP(1.0f + __expf(-x)); }
__device__ __forceinline__ float tanh_(float x){ return 1.0f - 2.0f*RCP(1.0f + __expf(2.0f*x)); }

// ---------------- weight pack kernel ----------------
// ws layout (bf16), frag = 64 lanes x 8 bf16 = 512 elems:
//  frags 0..143 : z-weights [hq 0..3][g 0..3][kst 0..8]; kst0 = Wi (k 0..7 real,
//                 8..15 zero-pad), kst 1..8 = Wh k-chunks of 16.
//  frags 144..175: W1 [nt 0..3][kst 0..7];  176..207: W2 same.
// frag element (lane,j): B[k = kst*16 + (lane>>5)*8 + j][n = colbase + (lane&31)]
__global__ void pack_weights(const float* __restrict__ Wi, const float* __restrict__ Wh,
                             const float* __restrict__ W1, const float* __restrict__ W2,
                             short* __restrict__ ws)
{
  int idx = blockIdx.x * 256 + threadIdx.x;
  if (idx >= 208 * 512) return;
  int f    = idx >> 9;
  int r    = idx & 511;
  int lane = r >> 3, j = r & 7;
  int kl   = ((lane >> 5) << 3) + j;     // k within 16
  int n32  = lane & 31;
  float v;
  if (f < 144){
    int hq = f / 36, rem = f % 36, g = rem / 9, kst = rem % 9;
    int col = g * 128 + hq * 32 + n32;
    if (kst == 0) v = (kl < 8) ? Wi[kl * 512 + col] : 0.0f;
    else          v = Wh[((kst - 1) * 16 + kl) * 512 + col];
  } else {
    int f2 = f - 144;                    // 0..63
    const float* W = (f2 < 32) ? W1 : W2;
    int f3 = f2 & 31;
    int nt = f3 >> 3, kst = f3 & 7;
    v = W[(kst * 16 + kl) * 128 + nt * 32 + n32];
  }
  ws[idx] = f2bf(v);
}

// ---------------- main kernel ----------------
__global__ __launch_bounds__(256, 2)
void lstm_mfma(FeatPtrs fp, const float* __restrict__ irr,
               const short* __restrict__ wsb,
               const float* __restrict__ bz, const float* __restrict__ b1,
               const float* __restrict__ b2, const float* __restrict__ Wout,
               const float* __restrict__ bout, float* __restrict__ out)
{
  __shared__ __align__(16) short xh[2][768];        // x hi/lo, 1 panel each
  __shared__ __align__(16) short hp[2][8 * 768];    // h hi/lo, 8 panels
  __shared__ __align__(16) short o1p[8 * 768];      // o1 single, 8 panels
  __shared__ __align__(16) float o2s[16 * 132];     // o2 fp32, padded rows
  __shared__ float WoutS[128];
  __shared__ float pS[16];

  const int t    = threadIdx.x;
  const int l    = t & 63;
  const int w    = t >> 6;
  const int ln31 = l & 31;
  const int half = l >> 5;
  const int r0   = blockIdx.x * 16;

  // weight fragments -> registers (coalesced dwordx4 loads)
  short8 Bz[4][9], B1f[8], B2f[8];
  {
    const short8* f8 = (const short8*)wsb;
#pragma unroll
    for (int g = 0; g < 4; ++g)
#pragma unroll
      for (int ks = 0; ks < 9; ++ks)
        Bz[g][ks] = f8[((w * 4 + g) * 9 + ks) * 64 + l];
#pragma unroll
    for (int ks = 0; ks < 8; ++ks) B1f[ks] = f8[(144 + w * 8 + ks) * 64 + l];
#pragma unroll
    for (int ks = 0; ks < 8; ++ks) B2f[ks] = f8[(176 + w * 8 + ks) * 64 + l];
  }
  float bzv[4];
#pragma unroll
  for (int g = 0; g < 4; ++g) bzv[g] = bz[g * 128 + w * 32 + ln31];
  const float b1v   = b1[w * 32 + ln31];
  const float b2v   = b2[w * 32 + ln31];
  const float bout0 = bout[0];
  if (t < 128) WoutS[t] = Wout[t];

  { // zero x panels, h panels, o1 panels (pad rows/cols must stay 0 forever)
    int* p = (int*)&xh[0][0];
    for (int i = t; i < 768;  i += 256) p[i] = 0;
    p = (int*)&hp[0][0];
    for (int i = t; i < 6144; i += 256) p[i] = 0;
    p = (int*)&o1p[0];
    for (int i = t; i < 3072; i += 256) p[i] = 0;
  }

  float cst[8];
#pragma unroll
  for (int i = 0; i < 8; ++i) cst[i] = 0.0f;

  const int aoff   = ln31 * 24 + half * 8;              // A-frag read offset (shorts)
  const int hcol   = w * 32 + ln31;                     // this lane's output col
  const int hwbase = (hcol >> 4) * 768 + (hcol & 15);   // activation write base
  __syncthreads();

  for (int step = 0; step < T_STEPS; ++step){
    if (t < 128){ // ---- gather 8 input features for 16 rows, split hi/lo ----
      int r = t >> 3, j = t & 7;
      float v;
      if (j < 7)               v = fp.f[j][(r0 + r) * T_STEPS + step];
      else if (step < WARM_N)  v = irr[(r0 + r) * WARM_N + step];
      else                     v = pS[r];               // autoregressive feedback
      short hi = f2bf(v);
      xh[0][r * 24 + j] = hi;
      xh[1][r * 24 + j] = f2bf(v - bf2f(hi));
    }
    __syncthreads();

    // ---- z = b + [x_hi+x_lo]@Wi + [h_hi+h_lo]@Wh  (4 gate tiles in-lane) ----
    float16 acc[4];
#pragma unroll
    for (int g = 0; g < 4; ++g)
#pragma unroll
      for (int r = 0; r < 16; ++r) acc[g][r] = bzv[g];
    {
      short8 a0 = *(const short8*)&xh[0][aoff];
      short8 a1 = *(const short8*)&xh[1][aoff];
#pragma unroll
      for (int g = 0; g < 4; ++g){
        acc[g] = __builtin_amdgcn_mfma_f32_32x32x16_bf16(a0, Bz[g][0], acc[g], 0, 0, 0);
        acc[g] = __builtin_amdgcn_mfma_f32_32x32x16_bf16(a1, Bz[g][0], acc[g], 0, 0, 0);
      }
    }
#pragma unroll
    for (int ks = 0; ks < 8; ++ks){
      short8 ah = *(const short8*)&hp[0][ks * 768 + aoff];
      short8 al = *(const short8*)&hp[1][ks * 768 + aoff];
#pragma unroll
      for (int g = 0; g < 4; ++g){
        acc[g] = __builtin_amdgcn_mfma_f32_32x32x16_bf16(ah, Bz[g][1 + ks], acc[g], 0, 0, 0);
        acc[g] = __builtin_amdgcn_mfma_f32_32x32x16_bf16(al, Bz[g][1 + ks], acc[g], 0, 0, 0);
      }
    }
    __syncthreads();   // all panel reads done before h rewrite

    // ---- gates (fp32, in-lane) on real rows only (regs r<8 = rows 0..15) ----
#pragma unroll
    for (int r = 0; r < 8; ++r){
      float zi = acc[0][r], zf = acc[1][r], zg = acc[2][r], zo = acc[3][r];
      float c2 = sigm(zf) * cst[r] + sigm(zi) * tanh_(zg);
      cst[r] = c2;
      float h2 = sigm(zo) * tanh_(c2);
      int row = (r & 3) + 8 * (r >> 2) + 4 * half;      // rows 0..15 for r<8
      short hi = f2bf(h2);
      hp[0][hwbase + row * 24] = hi;
      hp[1][hwbase + row * 24] = f2bf(h2 - bf2f(hi));
    }
    __syncthreads();

    // ---- MLP1: o1 = relu(h@W1 + b1) ----
    float16 m1;
#pragma unroll
    for (int r = 0; r < 16; ++r) m1[r] = b1v;
#pragma unroll
    for (int ks = 0; ks < 8; ++ks){
      short8 ah = *(const short8*)&hp[0][ks * 768 + aoff];
      m1 = __builtin_amdgcn_mfma_f32_32x32x16_bf16(ah, B1f[ks], m1, 0, 0, 0);
      short8 al = *(const short8*)&hp[1][ks * 768 + aoff];
      m1 = __builtin_amdgcn_mfma_f32_32x32x16_bf16(al, B1f[ks], m1, 0, 0, 0);
    }
#pragma unroll
    for (int r = 0; r < 8; ++r){
      int row = (r & 3) + 8 * (r >> 2) + 4 * half;
      o1p[hwbase + row * 24] = f2bf(fmaxf(m1[r], 0.0f));
    }
    __syncthreads();

    // ---- MLP2: o2 = relu(o1@W2 + b2), store fp32 ----
    float16 m2;
#pragma unroll
    for (int r = 0; r < 16; ++r) m2[r] = b2v;
#pragma unroll
    for (int ks = 0; ks < 8; ++ks){
      short8 a = *(const short8*)&o1p[ks * 768 + aoff];
      m2 = __builtin_amdgcn_mfma_f32_32x32x16_bf16(a, B2f[ks], m2, 0, 0, 0);
    }
#pragma unroll
    for (int r = 0; r < 8; ++r){
      int row = (r & 3) + 8 * (r >> 2) + 4 * half;
      o2s[row * 132 + hcol] = fmaxf(m2[r], 0.0f);
    }
    __syncthreads();

    // ---- head: p = o2 . Wout + bout (fp32 exact), 8 threads/row ----
    if (t < 128){
      int r = t >> 3, jj = t & 7;
      const float* orow = &o2s[r * 132 + jj * 16];
      const float* wrow = &WoutS[jj * 16];
      float s = 0.0f;
#pragma unroll
      for (int q = 0; q < 16; ++q) s += orow[q] * wrow[q];
      s += __shfl_down(s, 4, 8);
      s += __shfl_down(s, 2, 8);
      s += __shfl_down(s, 1, 8);
      if (jj == 0){
        float p = s + bout0;
        out[(r0 + r) * T_STEPS + step] = p;
        pS[r] = p;
      }
    }
    __syncthreads();   // pS/panels visible before next step
  }
}

extern "C" void kernel_launch(void* const* d_in, const int* in_sizes, int n_in,
                              void* d_out, int out_size, void* d_ws, size_t ws_size,
                              hipStream_t stream)
{
  (void)in_sizes; (void)n_in; (void)out_size; (void)ws_size;
  // inputs: 0..7 weather (unused), 8..14 time feats, 15 irradiance_in,
  // 16 Wi, 17 Wh, 18 b, 19 W1, 20 b1, 21 W2, 22 b2, 23 Wout, 24 bout
  FeatPtrs fp;
  for (int j = 0; j < 7; ++j) fp.f[j] = (const float*)d_in[8 + j];
  const float* irr  = (const float*)d_in[15];
  const float* Wi   = (const float*)d_in[16];
  const float* Wh   = (const float*)d_in[17];
  const float* bz   = (const float*)d_in[18];
  const float* W1   = (const float*)d_in[19];
  const float* b1   = (const float*)d_in[20];
  const float* W2   = (const float*)d_in[21];
  const float* b2   = (const float*)d_in[22];
  const float* Wout = (const float*)d_in[23];
  const float* bout = (const float*)d_in[24];

  short* ws = (short*)d_ws;                       // 208*512*2 = 208 KB used
  pack_weights<<<dim3(416), dim3(256), 0, stream>>>(Wi, Wh, W1, W2, ws);
  lstm_mfma<<<dim3(512), dim3(256), 0, stream>>>(
      fp, irr, ws, bz, b1, b2, Wout, bout, (float*)d_out);
}

// Round 2
// 319.193 us; speedup vs baseline: 1.8138x; 1.8138x over previous
//
#include <hip/hip_runtime.h>

// Fused LSTM(H=128) + 3-layer MLP head, bf16 MFMA (32x32x16), fp32 state.
// B=8192 rows, T=30 steps. 512 blocks x 256 threads (4 waves), 16 rows/block
// => 2 independent blocks/CU so one block's compute fills the other's
// LDS/barrier/trans latency. MFMA rows 16..31 are zero-pad; C/D regs r<8 hold
// exactly rows 0..15, so all VALU epilogues run on r<8 only.
// NOTE: __launch_bounds__(256,1) — NOT (256,2). The resident weight set is
// ~208 VGPRs/thread; capping at 256,2's 128-VGPR budget spills weights to
// scratch (measured: FETCH 4.7MB -> 1.39GB, dur 160 -> 492us). At the natural
// ~228 VGPR allocation, 2 waves/SIMD still fit (456 <= 512) and the 512-block
// grid gives 2 blocks/CU at runtime.
// - Weights live in VGPRs as pre-packed bf16 B-fragments (pack kernel -> d_ws).
// - Wave w owns output cols [32w,32w+32) of every GEMM; z-GEMM N-tiles at
//   g*128+32w for g=0..3 => (i,f,g,o) quadruple + c-state are in-lane.
// - Activations (x,h) use split bf16 hi+lo (error ~2^-17); o1 single bf16.
// - fp32: accumulators, c, gate nonlinearities, o2, output head, feedback p.
// - LDS A-panels: [kstep][32 rows][24 shorts] (16 data + 8 pad, 48B rows);
//   pad rows 16..31 stay zero for the whole kernel (never rewritten).

#define T_STEPS 30
#define WARM_N  24

typedef __attribute__((ext_vector_type(8)))  short short8;   // 8 bf16 = 4 VGPRs
typedef __attribute__((ext_vector_type(16))) float float16;  // MFMA 32x32 C/D

struct FeatPtrs { const float* f[7]; };

__device__ __forceinline__ short f2bf(float f){
  unsigned u = __float_as_uint(f);
  unsigned r = (u + 0x7fffu + ((u >> 16) & 1u)) >> 16;   // round-nearest-even
  return (short)r;
}
__device__ __forceinline__ float bf2f(short h){
  return __uint_as_float(((unsigned)(unsigned short)h) << 16);
}

#if __has_builtin(__builtin_amdgcn_rcpf)
#define RCP(x) __builtin_amdgcn_rcpf(x)
#else
#define RCP(x) (1.0f/(x))
#endif

__device__ __forceinline__ float sigm(float x){ return RCP(1.0f + __expf(-x)); }
__device__ __forceinline__ float tanh_(float x){ return 1.0f - 2.0f*RCP(1.0f + __expf(2.0f*x)); }

// ---------------- weight pack kernel ----------------
// ws layout (bf16), frag = 64 lanes x 8 bf16 = 512 elems:
//  frags 0..143 : z-weights [hq 0..3][g 0..3][kst 0..8]; kst0 = Wi (k 0..7 real,
//                 8..15 zero-pad), kst 1..8 = Wh k-chunks of 16.
//  frags 144..175: W1 [nt 0..3][kst 0..7];  176..207: W2 same.
// frag element (lane,j): B[k = kst*16 + (lane>>5)*8 + j][n = colbase + (lane&31)]
__global__ void pack_weights(const float* __restrict__ Wi, const float* __restrict__ Wh,
                             const float* __restrict__ W1, const float* __restrict__ W2,
                             short* __restrict__ ws)
{
  int idx = blockIdx.x * 256 + threadIdx.x;
  if (idx >= 208 * 512) return;
  int f    = idx >> 9;
  int r    = idx & 511;
  int lane = r >> 3, j = r & 7;
  int kl   = ((lane >> 5) << 3) + j;     // k within 16
  int n32  = lane & 31;
  float v;
  if (f < 144){
    int hq = f / 36, rem = f % 36, g = rem / 9, kst = rem % 9;
    int col = g * 128 + hq * 32 + n32;
    if (kst == 0) v = (kl < 8) ? Wi[kl * 512 + col] : 0.0f;
    else          v = Wh[((kst - 1) * 16 + kl) * 512 + col];
  } else {
    int f2 = f - 144;                    // 0..63
    const float* W = (f2 < 32) ? W1 : W2;
    int f3 = f2 & 31;
    int nt = f3 >> 3, kst = f3 & 7;
    v = W[(kst * 16 + kl) * 128 + nt * 32 + n32];
  }
  ws[idx] = f2bf(v);
}

// ---------------- main kernel ----------------
__global__ __launch_bounds__(256, 1)
void lstm_mfma(FeatPtrs fp, const float* __restrict__ irr,
               const short* __restrict__ wsb,
               const float* __restrict__ bz, const float* __restrict__ b1,
               const float* __restrict__ b2, const float* __restrict__ Wout,
               const float* __restrict__ bout, float* __restrict__ out)
{
  __shared__ __align__(16) short xh[2][768];        // x hi/lo, 1 panel each
  __shared__ __align__(16) short hp[2][8 * 768];    // h hi/lo, 8 panels
  __shared__ __align__(16) short o1p[8 * 768];      // o1 single, 8 panels
  __shared__ __align__(16) float o2s[16 * 132];     // o2 fp32, padded rows
  __shared__ float WoutS[128];
  __shared__ float pS[16];

  const int t    = threadIdx.x;
  const int l    = t & 63;
  const int w    = t >> 6;
  const int ln31 = l & 31;
  const int half = l >> 5;
  const int r0   = blockIdx.x * 16;

  // weight fragments -> registers (coalesced dwordx4 loads)
  short8 Bz[4][9], B1f[8], B2f[8];
  {
    const short8* f8 = (const short8*)wsb;
#pragma unroll
    for (int g = 0; g < 4; ++g)
#pragma unroll
      for (int ks = 0; ks < 9; ++ks)
        Bz[g][ks] = f8[((w * 4 + g) * 9 + ks) * 64 + l];
#pragma unroll
    for (int ks = 0; ks < 8; ++ks) B1f[ks] = f8[(144 + w * 8 + ks) * 64 + l];
#pragma unroll
    for (int ks = 0; ks < 8; ++ks) B2f[ks] = f8[(176 + w * 8 + ks) * 64 + l];
  }
  float bzv[4];
#pragma unroll
  for (int g = 0; g < 4; ++g) bzv[g] = bz[g * 128 + w * 32 + ln31];
  const float b1v   = b1[w * 32 + ln31];
  const float b2v   = b2[w * 32 + ln31];
  const float bout0 = bout[0];
  if (t < 128) WoutS[t] = Wout[t];

  { // zero x panels, h panels, o1 panels (pad rows/cols must stay 0 forever)
    int* p = (int*)&xh[0][0];
    for (int i = t; i < 768;  i += 256) p[i] = 0;
    p = (int*)&hp[0][0];
    for (int i = t; i < 6144; i += 256) p[i] = 0;
    p = (int*)&o1p[0];
    for (int i = t; i < 3072; i += 256) p[i] = 0;
  }

  float cst[8];
#pragma unroll
  for (int i = 0; i < 8; ++i) cst[i] = 0.0f;

  const int aoff   = ln31 * 24 + half * 8;              // A-frag read offset (shorts)
  const int hcol   = w * 32 + ln31;                     // this lane's output col
  const int hwbase = (hcol >> 4) * 768 + (hcol & 15);   // activation write base
  __syncthreads();

  for (int step = 0; step < T_STEPS; ++step){
    if (t < 128){ // ---- gather 8 input features for 16 rows, split hi/lo ----
      int r = t >> 3, j = t & 7;
      float v;
      if (j < 7)               v = fp.f[j][(r0 + r) * T_STEPS + step];
      else if (step < WARM_N)  v = irr[(r0 + r) * WARM_N + step];
      else                     v = pS[r];               // autoregressive feedback
      short hi = f2bf(v);
      xh[0][r * 24 + j] = hi;
      xh[1][r * 24 + j] = f2bf(v - bf2f(hi));
    }
    __syncthreads();

    // ---- z = b + [x_hi+x_lo]@Wi + [h_hi+h_lo]@Wh  (4 gate tiles in-lane) ----
    float16 acc[4];
#pragma unroll
    for (int g = 0; g < 4; ++g)
#pragma unroll
      for (int r = 0; r < 16; ++r) acc[g][r] = bzv[g];
    {
      short8 a0 = *(const short8*)&xh[0][aoff];
      short8 a1 = *(const short8*)&xh[1][aoff];
#pragma unroll
      for (int g = 0; g < 4; ++g){
        acc[g] = __builtin_amdgcn_mfma_f32_32x32x16_bf16(a0, Bz[g][0], acc[g], 0, 0, 0);
        acc[g] = __builtin_amdgcn_mfma_f32_32x32x16_bf16(a1, Bz[g][0], acc[g], 0, 0, 0);
      }
    }
#pragma unroll
    for (int ks = 0; ks < 8; ++ks){
      short8 ah = *(const short8*)&hp[0][ks * 768 + aoff];
      short8 al = *(const short8*)&hp[1][ks * 768 + aoff];
#pragma unroll
      for (int g = 0; g < 4; ++g){
        acc[g] = __builtin_amdgcn_mfma_f32_32x32x16_bf16(ah, Bz[g][1 + ks], acc[g], 0, 0, 0);
        acc[g] = __builtin_amdgcn_mfma_f32_32x32x16_bf16(al, Bz[g][1 + ks], acc[g], 0, 0, 0);
      }
    }
    __syncthreads();   // all panel reads done before h rewrite

    // ---- gates (fp32, in-lane) on real rows only (regs r<8 = rows 0..15) ----
#pragma unroll
    for (int r = 0; r < 8; ++r){
      float zi = acc[0][r], zf = acc[1][r], zg = acc[2][r], zo = acc[3][r];
      float c2 = sigm(zf) * cst[r] + sigm(zi) * tanh_(zg);
      cst[r] = c2;
      float h2 = sigm(zo) * tanh_(c2);
      int row = (r & 3) + 8 * (r >> 2) + 4 * half;      // rows 0..15 for r<8
      short hi = f2bf(h2);
      hp[0][hwbase + row * 24] = hi;
      hp[1][hwbase + row * 24] = f2bf(h2 - bf2f(hi));
    }
    __syncthreads();

    // ---- MLP1: o1 = relu(h@W1 + b1) ----
    float16 m1;
#pragma unroll
    for (int r = 0; r < 16; ++r) m1[r] = b1v;
#pragma unroll
    for (int ks = 0; ks < 8; ++ks){
      short8 ah = *(const short8*)&hp[0][ks * 768 + aoff];
      m1 = __builtin_amdgcn_mfma_f32_32x32x16_bf16(ah, B1f[ks], m1, 0, 0, 0);
      short8 al = *(const short8*)&hp[1][ks * 768 + aoff];
      m1 = __builtin_amdgcn_mfma_f32_32x32x16_bf16(al, B1f[ks], m1, 0, 0, 0);
    }
#pragma unroll
    for (int r = 0; r < 8; ++r){
      int row = (r & 3) + 8 * (r >> 2) + 4 * half;
      o1p[hwbase + row * 24] = f2bf(fmaxf(m1[r], 0.0f));
    }
    __syncthreads();

    // ---- MLP2: o2 = relu(o1@W2 + b2), store fp32 ----
    float16 m2;
#pragma unroll
    for (int r = 0; r < 16; ++r) m2[r] = b2v;
#pragma unroll
    for (int ks = 0; ks < 8; ++ks){
      short8 a = *(const short8*)&o1p[ks * 768 + aoff];
      m2 = __builtin_amdgcn_mfma_f32_32x32x16_bf16(a, B2f[ks], m2, 0, 0, 0);
    }
#pragma unroll
    for (int r = 0; r < 8; ++r){
      int row = (r & 3) + 8 * (r >> 2) + 4 * half;
      o2s[row * 132 + hcol] = fmaxf(m2[r], 0.0f);
    }
    __syncthreads();

    // ---- head: p = o2 . Wout + bout (fp32 exact), 8 threads/row ----
    if (t < 128){
      int r = t >> 3, jj = t & 7;
      const float* orow = &o2s[r * 132 + jj * 16];
      const float* wrow = &WoutS[jj * 16];
      float s = 0.0f;
#pragma unroll
      for (int q = 0; q < 16; ++q) s += orow[q] * wrow[q];
      s += __shfl_down(s, 4, 8);
      s += __shfl_down(s, 2, 8);
      s += __shfl_down(s, 1, 8);
      if (jj == 0){
        float p = s + bout0;
        out[(r0 + r) * T_STEPS + step] = p;
        pS[r] = p;
      }
    }
    __syncthreads();   // pS/panels visible before next step
  }
}

extern "C" void kernel_launch(void* const* d_in, const int* in_sizes, int n_in,
                              void* d_out, int out_size, void* d_ws, size_t ws_size,
                              hipStream_t stream)
{
  (void)in_sizes; (void)n_in; (void)out_size; (void)ws_size;
  // inputs: 0..7 weather (unused), 8..14 time feats, 15 irradiance_in,
  // 16 Wi, 17 Wh, 18 b, 19 W1, 20 b1, 21 W2, 22 b2, 23 Wout, 24 bout
  FeatPtrs fp;
  for (int j = 0; j < 7; ++j) fp.f[j] = (const float*)d_in[8 + j];
  const float* irr  = (const float*)d_in[15];
  const float* Wi   = (const float*)d_in[16];
  const float* Wh   = (const float*)d_in[17];
  const float* bz   = (const float*)d_in[18];
  const float* W1   = (const float*)d_in[19];
  const float* b1   = (const float*)d_in[20];
  const float* W2   = (const float*)d_in[21];
  const float* b2   = (const float*)d_in[22];
  const float* Wout = (const float*)d_in[23];
  const float* bout = (const float*)d_in[24];

  short* ws = (short*)d_ws;                       // 208*512*2 = 208 KB used
  pack_weights<<<dim3(416), dim3(256), 0, stream>>>(Wi, Wh, W1, W2, ws);
  lstm_mfma<<<dim3(512), dim3(256), 0, stream>>>(
      fp, irr, ws, bz, b1, b2, Wout, bout, (float*)d_out);
}

// Round 3
// 224.690 us; speedup vs baseline: 2.5767x; 1.4206x over previous
//
#include <hip/hip_runtime.h>

// Fused LSTM(H=128) + 3-layer MLP head, bf16 MFMA (16x16x32), fp32 state.
// B=8192 rows, T=30 steps. 256 blocks x 512 threads (8 waves), 32 rows/block.
// OCCUPANCY DESIGN (rounds 0-2 lesson): gfx950 VGPR+accum file is unified,
// 512 regs/SIMD; total regs must be <=256 for 2 waves/SIMD. The old 4-wave
// 32x32x16 design needed 208 weight VGPRs + 64 acc = >256 -> 1 wave/SIMD
// (Occupancy 11%). This 8-wave 16x16x32 retile: each wave owns 16 output
// cols; K=32 fragments reused for hi+lo passes => weights = 112 VGPRs
// (Bz 4gx5 + W1 4 + W2 4 frags), acc 32 => peak ~190. __launch_bounds__(512,2)
// caps at 256 (60+ regs headroom, unlike round 1's impossible 128 cap).
// One 8-wave block/CU = 2 waves/SIMD -> latency hiding between barriers.
// - x-kstep packs x_hi (k0..7) | x_lo (k8..15) with Wi replicated in B-frag.
// - h/o1 B-frags used for both hi and lo A-panels (same weights).
// - 16x16x32 layouts: A/B: row|col=lane&15, k=(lane>>4)*8+j; C/D: col=lane&15,
//   row=(lane>>4)*4+reg (m89-verified).
// - A-panels [16 rows][40 shorts] (32 data + 8 pad): 16B-aligned b128 reads,
//   banks perfectly balanced (8 words/bank).
// - Precision identical to passing config: hi/lo split x,h; single-bf16 o1;
//   fp32 acc, gates, o2, head, feedback.

#define T_STEPS 30
#define WARM_N  24

typedef __attribute__((ext_vector_type(8)))  short short8;   // 8 bf16 = 4 VGPRs
typedef __attribute__((ext_vector_type(4)))  float float4v;  // MFMA 16x16 C/D

struct FeatPtrs { const float* f[7]; };

__device__ __forceinline__ short f2bf(float f){
  unsigned u = __float_as_uint(f);
  unsigned r = (u + 0x7fffu + ((u >> 16) & 1u)) >> 16;   // round-nearest-even
  return (short)r;
}
__device__ __forceinline__ float bf2f(short h){
  return __uint_as_float(((unsigned)(unsigned short)h) << 16);
}

#if __has_builtin(__builtin_amdgcn_rcpf)
#define RCP(x) __builtin_amdgcn_rcpf(x)
#else
#define RCP(x) (1.0f/(x))
#endif

__device__ __forceinline__ float sigm(float x){ return RCP(1.0f + __expf(-x)); }
__device__ __forceinline__ float tanh_(float x){ return 1.0f - 2.0f*RCP(1.0f + __expf(2.0f*x)); }

// ---------------- weight pack kernel ----------------
// 224 frags of 512 bf16 (1 KB each), frag elem (lane,j):
//   col16 = lane&15, kk = (lane>>4)*8 + j  (K=32 per fragment)
// frags 0..159 : z-weights [w 0..7][g 0..3][ks 0..4]
//   ks=0: x-frag: kk<8 -> Wi[kk][col], kk 8..15 -> Wi[kk-8][col] (lo replica),
//         kk>=16 -> 0;  ks 1..4: Wh[(ks-1)*32+kk][col];  col = g*128+w*16+col16
// frags 160..191: W1 [w][ks 0..3]: W1[ks*32+kk][w*16+col16]
// frags 192..223: W2 same layout.
__global__ void pack_weights(const float* __restrict__ Wi, const float* __restrict__ Wh,
                             const float* __restrict__ W1, const float* __restrict__ W2,
                             short* __restrict__ ws)
{
  int idx = blockIdx.x * 256 + threadIdx.x;
  if (idx >= 224 * 512) return;
  int f    = idx >> 9;
  int r    = idx & 511;
  int lane = r >> 3, j = r & 7;
  int kk   = ((lane >> 4) << 3) + j;     // 0..31
  int c16  = lane & 15;
  float v = 0.0f;
  if (f < 160){
    int w = f / 20, rem = f % 20, g = rem / 5, ks = rem % 5;
    int col = g * 128 + w * 16 + c16;
    if (ks == 0){
      if (kk < 8)        v = Wi[kk * 512 + col];
      else if (kk < 16)  v = Wi[(kk - 8) * 512 + col];
      else               v = 0.0f;
    } else {
      v = Wh[((ks - 1) * 32 + kk) * 512 + col];
    }
  } else {
    int f2 = f - 160;                    // 0..63
    const float* W = (f2 < 32) ? W1 : W2;
    int f3 = f2 & 31;
    int w = f3 >> 2, ks = f3 & 3;
    v = W[(ks * 32 + kk) * 128 + w * 16 + c16];
  }
  ws[idx] = f2bf(v);
}

// ---------------- main kernel ----------------
__global__ __launch_bounds__(512, 2)
void lstm_mfma(FeatPtrs fp, const float* __restrict__ irr,
               const short* __restrict__ wsb,
               const float* __restrict__ bz, const float* __restrict__ b1,
               const float* __restrict__ b2, const float* __restrict__ Wout,
               const float* __restrict__ bout, float* __restrict__ out)
{
  // A-panels: [kstep][m-tile 0..1][16 rows][40 shorts] (k 0..31 data + 8 pad)
  __shared__ __align__(16) short xp [2 * 640];      // x: k0..7 hi, k8..15 lo
  __shared__ __align__(16) short hhi[4 * 1280];     // h hi, 4 ksteps
  __shared__ __align__(16) short hlo[4 * 1280];     // h lo
  __shared__ __align__(16) short o1p[4 * 1280];     // o1 single bf16
  __shared__ __align__(16) float o2s[32 * 132];     // o2 fp32, padded rows
  __shared__ float WoutS[128];
  __shared__ float pS[32];

  const int t   = threadIdx.x;
  const int l   = t & 63;
  const int w   = t >> 6;        // wave 0..7, owns cols [16w,16w+16)
  const int c16 = l & 15;
  const int kq  = l >> 4;        // 0..3
  const int r0  = blockIdx.x * 32;

  // weight fragments -> registers (coalesced dwordx4 loads)
  short8 Bz[4][5], B1f[4], B2f[4];
  {
    const short8* f8 = (const short8*)wsb;
#pragma unroll
    for (int g = 0; g < 4; ++g)
#pragma unroll
      for (int ks = 0; ks < 5; ++ks)
        Bz[g][ks] = f8[((w * 4 + g) * 5 + ks) * 64 + l];
#pragma unroll
    for (int ks = 0; ks < 4; ++ks) B1f[ks] = f8[(160 + w * 4 + ks) * 64 + l];
#pragma unroll
    for (int ks = 0; ks < 4; ++ks) B2f[ks] = f8[(192 + w * 4 + ks) * 64 + l];
  }
  float bzv[4];
#pragma unroll
  for (int g = 0; g < 4; ++g) bzv[g] = bz[g * 128 + w * 16 + c16];
  const float b1v   = b1[w * 16 + c16];
  const float b2v   = b2[w * 16 + c16];
  const float bout0 = bout[0];
  if (t < 128) WoutS[t] = Wout[t];

  { // zero x panel (k16..31 must stay 0) and h panels (h0 = 0)
    int* p = (int*)xp;
    for (int i = t; i < 640;  i += 512) p[i] = 0;
    p = (int*)hhi;
    for (int i = t; i < 2560; i += 512) p[i] = 0;
    p = (int*)hlo;
    for (int i = t; i < 2560; i += 512) p[i] = 0;
  }

  float cst[8];
#pragma unroll
  for (int i = 0; i < 8; ++i) cst[i] = 0.0f;

  const int aoff = c16 * 40 + kq * 8;      // A-frag read offset (shorts)
  const int kin  = (w & 1) * 16 + c16;     // k index within kstep for h-col
  const int wb   = (w >> 1) * 1280 + kin;  // h/o1 write base (hk panel + kin)
  __syncthreads();

  for (int step = 0; step < T_STEPS; ++step){
    if (t < 256){ // ---- gather 8 input features for 32 rows, split hi/lo ----
      int r = t >> 3, j = t & 7;
      float v;
      if (j < 7)               v = fp.f[j][(r0 + r) * T_STEPS + step];
      else if (step < WARM_N)  v = irr[(r0 + r) * WARM_N + step];
      else                     v = pS[r];               // autoregressive feedback
      int base = (r >> 4) * 640 + (r & 15) * 40 + j;
      short hi = f2bf(v);
      xp[base]     = hi;
      xp[base + 8] = f2bf(v - bf2f(hi));
    }
    __syncthreads();

    // ---- z = b + x@Wi + [h_hi+h_lo]@Wh  (4 gates x 2 M-tiles in-lane) ----
    float4v acc[4][2];
#pragma unroll
    for (int g = 0; g < 4; ++g)
#pragma unroll
      for (int m = 0; m < 2; ++m)
#pragma unroll
        for (int r = 0; r < 4; ++r) acc[g][m][r] = bzv[g];
    {
      short8 a0 = *(const short8*)&xp[aoff];
      short8 a1 = *(const short8*)&xp[640 + aoff];
#pragma unroll
      for (int g = 0; g < 4; ++g){
        acc[g][0] = __builtin_amdgcn_mfma_f32_16x16x32_bf16(a0, Bz[g][0], acc[g][0], 0, 0, 0);
        acc[g][1] = __builtin_amdgcn_mfma_f32_16x16x32_bf16(a1, Bz[g][0], acc[g][1], 0, 0, 0);
      }
    }
#pragma unroll
    for (int ks = 0; ks < 4; ++ks){
      short8 ah0 = *(const short8*)&hhi[ks * 1280 + aoff];
      short8 al0 = *(const short8*)&hlo[ks * 1280 + aoff];
      short8 ah1 = *(const short8*)&hhi[ks * 1280 + 640 + aoff];
      short8 al1 = *(const short8*)&hlo[ks * 1280 + 640 + aoff];
#pragma unroll
      for (int g = 0; g < 4; ++g){
        acc[g][0] = __builtin_amdgcn_mfma_f32_16x16x32_bf16(ah0, Bz[g][1 + ks], acc[g][0], 0, 0, 0);
        acc[g][0] = __builtin_amdgcn_mfma_f32_16x16x32_bf16(al0, Bz[g][1 + ks], acc[g][0], 0, 0, 0);
        acc[g][1] = __builtin_amdgcn_mfma_f32_16x16x32_bf16(ah1, Bz[g][1 + ks], acc[g][1], 0, 0, 0);
        acc[g][1] = __builtin_amdgcn_mfma_f32_16x16x32_bf16(al1, Bz[g][1 + ks], acc[g][1], 0, 0, 0);
      }
    }
    __syncthreads();   // all panel reads done before h rewrite

    // ---- gates (fp32, in-lane), update c, write h hi/lo panels ----
#pragma unroll
    for (int m = 0; m < 2; ++m)
#pragma unroll
      for (int r = 0; r < 4; ++r){
        float zi = acc[0][m][r], zf = acc[1][m][r], zg = acc[2][m][r], zo = acc[3][m][r];
        float c2 = sigm(zf) * cst[m * 4 + r] + sigm(zi) * tanh_(zg);
        cst[m * 4 + r] = c2;
        float h2 = sigm(zo) * tanh_(c2);
        int addr = wb + m * 640 + (kq * 4 + r) * 40;    // row = kq*4+r (C/D map)
        short hi = f2bf(h2);
        hhi[addr] = hi;
        hlo[addr] = f2bf(h2 - bf2f(hi));
      }
    __syncthreads();

    // ---- MLP1: o1 = relu(h@W1 + b1) ----
    float4v m1[2];
#pragma unroll
    for (int m = 0; m < 2; ++m)
#pragma unroll
      for (int r = 0; r < 4; ++r) m1[m][r] = b1v;
#pragma unroll
    for (int ks = 0; ks < 4; ++ks){
#pragma unroll
      for (int m = 0; m < 2; ++m){
        short8 ah = *(const short8*)&hhi[ks * 1280 + m * 640 + aoff];
        m1[m] = __builtin_amdgcn_mfma_f32_16x16x32_bf16(ah, B1f[ks], m1[m], 0, 0, 0);
        short8 al = *(const short8*)&hlo[ks * 1280 + m * 640 + aoff];
        m1[m] = __builtin_amdgcn_mfma_f32_16x16x32_bf16(al, B1f[ks], m1[m], 0, 0, 0);
      }
    }
#pragma unroll
    for (int m = 0; m < 2; ++m)
#pragma unroll
      for (int r = 0; r < 4; ++r){
        int addr = wb + m * 640 + (kq * 4 + r) * 40;
        o1p[addr] = f2bf(fmaxf(m1[m][r], 0.0f));
      }
    __syncthreads();

    // ---- MLP2: o2 = relu(o1@W2 + b2), store fp32 ----
    float4v m2[2];
#pragma unroll
    for (int m = 0; m < 2; ++m)
#pragma unroll
      for (int r = 0; r < 4; ++r) m2[m][r] = b2v;
#pragma unroll
    for (int ks = 0; ks < 4; ++ks){
#pragma unroll
      for (int m = 0; m < 2; ++m){
        short8 a = *(const short8*)&o1p[ks * 1280 + m * 640 + aoff];
        m2[m] = __builtin_amdgcn_mfma_f32_16x16x32_bf16(a, B2f[ks], m2[m], 0, 0, 0);
      }
    }
#pragma unroll
    for (int m = 0; m < 2; ++m)
#pragma unroll
      for (int r = 0; r < 4; ++r)
        o2s[(m * 16 + kq * 4 + r) * 132 + w * 16 + c16] = fmaxf(m2[m][r], 0.0f);
    __syncthreads();

    // ---- head: p = o2 . Wout + bout (fp32 exact), 8 threads/row ----
    if (t < 256){
      int r = t >> 3, jj = t & 7;
      const float* orow = &o2s[r * 132 + jj * 16];
      const float* wrow = &WoutS[jj * 16];
      float s = 0.0f;
#pragma unroll
      for (int q = 0; q < 16; ++q) s += orow[q] * wrow[q];
      s += __shfl_down(s, 4, 8);
      s += __shfl_down(s, 2, 8);
      s += __shfl_down(s, 1, 8);
      if (jj == 0){
        float p = s + bout0;
        out[(r0 + r) * T_STEPS + step] = p;
        pS[r] = p;
      }
    }
    __syncthreads();   // pS/panels visible before next step
  }
}

extern "C" void kernel_launch(void* const* d_in, const int* in_sizes, int n_in,
                              void* d_out, int out_size, void* d_ws, size_t ws_size,
                              hipStream_t stream)
{
  (void)in_sizes; (void)n_in; (void)out_size; (void)ws_size;
  // inputs: 0..7 weather (unused), 8..14 time feats, 15 irradiance_in,
  // 16 Wi, 17 Wh, 18 b, 19 W1, 20 b1, 21 W2, 22 b2, 23 Wout, 24 bout
  FeatPtrs fp;
  for (int j = 0; j < 7; ++j) fp.f[j] = (const float*)d_in[8 + j];
  const float* irr  = (const float*)d_in[15];
  const float* Wi   = (const float*)d_in[16];
  const float* Wh   = (const float*)d_in[17];
  const float* bz   = (const float*)d_in[18];
  const float* W1   = (const float*)d_in[19];
  const float* b1   = (const float*)d_in[20];
  const float* W2   = (const float*)d_in[21];
  const float* b2   = (const float*)d_in[22];
  const float* Wout = (const float*)d_in[23];
  const float* bout = (const float*)d_in[24];

  short* ws = (short*)d_ws;                       // 224*512*2 = 224 KB used
  pack_weights<<<dim3(448), dim3(256), 0, stream>>>(Wi, Wh, W1, W2, ws);
  lstm_mfma<<<dim3(256), dim3(512), 0, stream>>>(
      fp, irr, ws, bz, b1, b2, Wout, bout, (float*)d_out);
}